// Round 10
// baseline (108.905 us; speedup 1.0000x reference)
//
#include <hip/hip_runtime.h>
#include <stdint.h>

#define NUM_PTS 1024
#define NBATCH 128
#define BTHREADS 128                 // chamfer block (2 waves)
#define RTHREADS 256
#define NJC 16                       // j-chunks per batch
#define JC_PTS 64                    // recon points per chunk
#define CHAMF_SCALE (1.0f / 1024.0f)
#define KLD_SCALE   (-0.5f * 0.1f / 32.0f)

// ws floats:
//   [0, 512K)        qsoa: {x,y,z,q2} float4 per recon pt [NBATCH][NUM_PTS] = 2 MB
//   [512K, 512K+2M)  row partials [NJC][NBATCH][NUM_PTS] = 8 MB
#define QSOA_FLOATS   (NBATCH * NUM_PTS * 4)
#define ROW_JC_STRIDE (NBATCH * NUM_PTS)        // 131072

// Constant-addrspace FLOAT pointer (float4 copy-ctor can't bind an AS(4)
// reference — R8 compile fail). Scalar loads through this are legal; the
// compiler merges adjacent wave-uniform loads into s_load_dwordx4/x8 (SMEM
// pipe + scalar cache) so the q-stream costs no LDS or VMEM issue slots.
typedef const __attribute__((address_space(4))) float* cfp;

// Pack recon into {x,y,z,q2} so q2 is precomputed once per point.
__global__ __launch_bounds__(RTHREADS) void prep_kernel(
    const float* __restrict__ recon_x, float* __restrict__ qsoa)
{
    const int b = blockIdx.x;
    const float4* __restrict__ src = (const float4*)(recon_x + (size_t)b * NUM_PTS * 3);
    float4* __restrict__ dst = (float4*)qsoa + (size_t)b * NUM_PTS;
    const int t = threadIdx.x;                   // 4 points per thread
    const float4 A = src[3 * t + 0];
    const float4 B = src[3 * t + 1];
    const float4 C = src[3 * t + 2];
    dst[4 * t + 0] = make_float4(A.x, A.y, A.z, fmaf(A.x, A.x, fmaf(A.y, A.y, A.z * A.z)));
    dst[4 * t + 1] = make_float4(A.w, B.x, B.y, fmaf(A.w, A.w, fmaf(B.x, B.x, B.y * B.y)));
    dst[4 * t + 2] = make_float4(B.z, B.w, C.x, fmaf(B.z, B.z, fmaf(B.w, B.w, C.x * C.x)));
    dst[4 * t + 3] = make_float4(C.y, C.z, C.w, fmaf(C.y, C.y, fmaf(C.z, C.z, C.w * C.w)));
}

// SYMMETRIC chamfer: each d(i,j) computed ONCE serves both directions
// (134M evals instead of 268M). 2048 blocks = (b, jc): all 1024 x-rows
// (8/thread) x one 64-pt recon chunk. Row-side: partial mins -> ws (16
// chunks). Col-side: mins are COMPLETE in-block (all i present) -> pair-fold
// via shfl_xor(1), LDS candidates [64][65], post-pass, one atomicAdd.
// d' = r2 - 2x.q seeded with r2 (VGPR) so every fma has <=1 SGPR operand;
// q2 enters as a scalar add on each side.
__global__ __launch_bounds__(BTHREADS, 4) void chamfer_sym(
    const float* __restrict__ x,
    const float* __restrict__ qsoa,
    float* __restrict__ ws_row,
    float* __restrict__ out)
{
    const int b  = blockIdx.x >> 4;
    const int jc = blockIdx.x & 15;
    const int tid = threadIdx.x;
    const int slot = tid >> 1;

    cfp qs = (cfp)(uintptr_t)(qsoa + ((size_t)b * NUM_PTS + jc * JC_PTS) * 4);

    // --- own 8 contiguous x-rows: 6 coalesced float4 loads
    const float* rp = x + (size_t)b * NUM_PTS * 3;
    float buf[24];
    {
        const float4* __restrict__ s4 = (const float4*)(rp + 24 * tid);
        float4* bp = (float4*)buf;
#pragma unroll
        for (int i = 0; i < 6; ++i) bp[i] = s4[i];
    }
    float vx[8], vy[8], vz[8], r2[8], m[8];
#pragma unroll
    for (int k = 0; k < 8; ++k) {
        const float px = buf[3 * k], py = buf[3 * k + 1], pz = buf[3 * k + 2];
        r2[k] = fmaf(px, px, fmaf(py, py, pz * pz));
        vx[k] = -2.0f * px;
        vy[k] = -2.0f * py;
        vz[k] = -2.0f * pz;
        m[k]  = 1e30f;
    }

    __shared__ float scol[JC_PTS][65];    // pair-folded col candidates (full d)
    __shared__ float red[2];

    auto pair_eval = [&](float qax, float qay, float qaz, float qaw,
                         float qbx, float qby, float qbz, float qbw,
                         int ja, int jb) {
        float d0[8], d1[8];
#pragma unroll
        for (int r = 0; r < 8; ++r)
            d0[r] = fmaf(vx[r], qax, fmaf(vy[r], qay, fmaf(vz[r], qaz, r2[r])));
#pragma unroll
        for (int r = 0; r < 8; ++r)
            d1[r] = fmaf(vx[r], qbx, fmaf(vy[r], qby, fmaf(vz[r], qbz, r2[r])));
#pragma unroll
        for (int r = 0; r < 8; ++r)                        // row: add q2 -> min3
            m[r] = fminf(fminf(m[r], d0[r] + qaw), d1[r] + qbw);
        // col: tree over 8 rows, then + q2 once
        float c0 = fminf(fminf(fminf(d0[0], d0[1]), fminf(d0[2], d0[3])),
                         fminf(fminf(d0[4], d0[5]), fminf(d0[6], d0[7]))) + qaw;
        float c1 = fminf(fminf(fminf(d1[0], d1[1]), fminf(d1[2], d1[3])),
                         fminf(fminf(d1[4], d1[5]), fminf(d1[6], d1[7]))) + qbw;
        c0 = fminf(c0, __shfl_xor(c0, 1, 64));             // pair fold
        c1 = fminf(c1, __shfl_xor(c1, 1, 64));
        if (!(tid & 1)) { scol[ja][slot] = c0; scol[jb][slot] = c1; }
    };

    // --- 16 groups x 4 j over the 64-pt chunk; q via merged s_load (SMEM)
#pragma unroll 2
    for (int g = 0; g < 16; ++g) {
        const int o = 16 * g;
        const float a0 = qs[o + 0],  a1 = qs[o + 1],  a2 = qs[o + 2],  a3 = qs[o + 3];
        const float b0 = qs[o + 4],  b1 = qs[o + 5],  b2 = qs[o + 6],  b3 = qs[o + 7];
        const float c0 = qs[o + 8],  c1 = qs[o + 9],  c2 = qs[o + 10], c3 = qs[o + 11];
        const float e0 = qs[o + 12], e1 = qs[o + 13], e2 = qs[o + 14], e3 = qs[o + 15];
        pair_eval(a0, a1, a2, a3, b0, b1, b2, b3, 4 * g + 0, 4 * g + 1);
        pair_eval(c0, c1, c2, c3, e0, e1, e2, e3, 4 * g + 2, 4 * g + 3);
    }

    // --- row partials: 8 contiguous values -> 2 float4 stores
    float4* dst = (float4*)(ws_row + (size_t)jc * ROW_JC_STRIDE + b * NUM_PTS + 8 * tid);
    dst[0] = make_float4(m[0], m[1], m[2], m[3]);
    dst[1] = make_float4(m[4], m[5], m[6], m[7]);

    // --- col finish: thread t handles (j = t>>1, half = t&1): 32-value min
    __syncthreads();
    {
        const int j = tid >> 1, h = tid & 1;
        float cm = scol[j][h * 32];
#pragma unroll
        for (int k = 1; k < 32; ++k) cm = fminf(cm, scol[j][h * 32 + k]);
        cm = fminf(cm, __shfl_xor(cm, 1, 64));             // halves combine
        float v = (h == 0) ? cm * CHAMF_SCALE : 0.0f;      // each j counted once
        for (int off = 32; off > 0; off >>= 1)
            v += __shfl_down(v, off, 64);
        if ((tid & 63) == 0) red[tid >> 6] = v;
        __syncthreads();
        if (tid == 0) atomicAdd(out, red[0] + red[1]);
    }
}

// Row side: fold 16 chunk partials per row, sum, fold in KLD.
// 128 blocks x 256 threads: 4 rows/thread via float4; one block per batch.
__global__ __launch_bounds__(RTHREADS) void reduce_kernel(
    const float* __restrict__ ws_row,
    const float* __restrict__ mu,
    const float* __restrict__ logvar,
    float* __restrict__ out)
{
    const int b  = blockIdx.x;
    const int iv = threadIdx.x * 4;
    const float4* p = (const float4*)(ws_row + (size_t)b * NUM_PTS + iv);
    float4 mn = p[0];
#pragma unroll
    for (int c = 1; c < NJC; ++c) {
        const float4 q = p[c * (ROW_JC_STRIDE / 4)];
        mn.x = fminf(mn.x, q.x);
        mn.y = fminf(mn.y, q.y);
        mn.z = fminf(mn.z, q.z);
        mn.w = fminf(mn.w, q.w);
    }
    float v = (mn.x + mn.y + mn.z + mn.w) * CHAMF_SCALE;

    if (blockIdx.x < 16) {                                 // 16*256 = 4096 latents
        const int t = blockIdx.x * RTHREADS + threadIdx.x;
        const float lv = logvar[t];
        const float mm = mu[t];
        v += (1.0f + lv - mm * mm - expf(lv)) * KLD_SCALE;
    }

    for (int off = 32; off > 0; off >>= 1)
        v += __shfl_down(v, off, 64);

    __shared__ float red[RTHREADS / 64];
    const int lane = threadIdx.x & 63;
    const int wv   = threadIdx.x >> 6;
    if (lane == 0) red[wv] = v;
    __syncthreads();
    if (threadIdx.x == 0) {
        float sum = 0.f;
        for (int w = 0; w < RTHREADS / 64; ++w) sum += red[w];
        atomicAdd(out, sum);
    }
}

extern "C" void kernel_launch(void* const* d_in, const int* in_sizes, int n_in,
                              void* d_out, int out_size, void* d_ws, size_t ws_size,
                              hipStream_t stream) {
    const float* recon_x = (const float*)d_in[0];
    const float* x       = (const float*)d_in[1];
    const float* mu      = (const float*)d_in[2];
    const float* logvar  = (const float*)d_in[3];
    float* out    = (float*)d_out;
    float* qsoa   = (float*)d_ws;                  // 2 MB
    float* ws_row = (float*)d_ws + QSOA_FLOATS;    // 8 MB

    (void)hipMemsetAsync(out, 0, sizeof(float), stream);

    prep_kernel<<<NBATCH, RTHREADS, 0, stream>>>(recon_x, qsoa);
    chamfer_sym<<<NBATCH * NJC, BTHREADS, 0, stream>>>(x, qsoa, ws_row, out);
    reduce_kernel<<<NBATCH, RTHREADS, 0, stream>>>(ws_row, mu, logvar, out);
}

// Round 11
// 93.862 us; speedup vs baseline: 1.1603x; 1.1603x over previous
//
#include <hip/hip_runtime.h>

#define NUM_PTS 1024
#define NBATCH 128
#define BT 128                       // chamfer block: wave0 = dir0, wave1 = dir1
#define RT 256                       // reduce block
#define NJC 16                       // q-chunks per direction
#define JC 64                        // points per chunk
#define R 16                         // rows per thread (64 lanes x 16 = 1024 rows/wave)
#define CHAMF_SCALE (1.0f / 1024.0f)
#define KLD_SCALE   (-0.5f * 0.1f / 32.0f)

// ws: float [2][NJC][NBATCH][NUM_PTS] row partials = 16.8 MB.
#define WS_CHUNK (NBATCH * NUM_PTS)          // 131072
#define WS_DIR   (NJC * WS_CHUNK)            // 2097152

// 2048 blocks = (b, chunk); 8 blocks/CU = 16 waves/CU = 4 waves/SIMD (same
// TLP as R7). R=16 fixes R7's pipe parity: per wave per 4-qpt group,
// LDS = 4 ds_read_b128 (~48 cyc) vs VALU = 224 insts (~448 cyc) -> LDS at
// 43% of VALU (R7: 86% -> both saturated -> 60% duty). Wave w handles dir w:
// dir0 rows=x / q=recon (ref loss_2), dir1 rows=recon / q=x (loss_1); each
// wave stages its OWN 64-pt q-chunk as {x,y,z,q2} planes, 1 pt/lane.
// r2 is recomputed in the epilogue from vx,vy,vz (saves 16 VGPRs).
__global__ __launch_bounds__(BT, 4) void chamfer_part(
    const float* __restrict__ recon_x,
    const float* __restrict__ x,
    float* __restrict__ ws)
{
    const int b  = blockIdx.x >> 4;
    const int c  = blockIdx.x & 15;
    const int w  = threadIdx.x >> 6;         // wave = direction
    const int lt = threadIdx.x & 63;

    // --- stage this wave's q-chunk: planes {x,y,z,q2}
    __shared__ float sq[2][4][JC];           // 2 KB
    {
        const float* qsrc = (w == 0 ? recon_x : x)
                            + (size_t)b * NUM_PTS * 3 + (size_t)c * JC * 3 + 3 * lt;
        const float qx = qsrc[0], qy = qsrc[1], qz = qsrc[2];
        sq[w][0][lt] = qx;
        sq[w][1][lt] = qy;
        sq[w][2][lt] = qz;
        sq[w][3][lt] = fmaf(qx, qx, fmaf(qy, qy, qz * qz));
    }

    // --- own 16 contiguous rows: 12 float4 loads, -2*coord kept (r2 later)
    const float* rp = (w == 0 ? x : recon_x) + (size_t)b * NUM_PTS * 3;
    float vx[R], vy[R], vz[R], m[R];
    {
        const float4* __restrict__ s4 = (const float4*)(rp + 48 * lt);
        float buf[48];
        float4* bp = (float4*)buf;
#pragma unroll
        for (int i = 0; i < 12; ++i) bp[i] = s4[i];
#pragma unroll
        for (int k = 0; k < R; ++k) {
            vx[k] = -2.0f * buf[3 * k + 0];
            vy[k] = -2.0f * buf[3 * k + 1];
            vz[k] = -2.0f * buf[3 * k + 2];
            m[k]  = 1e30f;
        }
    }
    __syncthreads();

    // --- 16 groups x 4 qpts; d = q2 - 2 p.q seeded from the q2 LDS plane
    const float4* __restrict__ qxp = (const float4*)sq[w][0];
    const float4* __restrict__ qyp = (const float4*)sq[w][1];
    const float4* __restrict__ qzp = (const float4*)sq[w][2];
    const float4* __restrict__ q2p = (const float4*)sq[w][3];
#pragma unroll 2
    for (int g = 0; g < JC / 4; ++g) {
        const float4 qx = qxp[g];
        const float4 qy = qyp[g];
        const float4 qz = qzp[g];
        const float4 q2 = q2p[g];
#pragma unroll
        for (int r = 0; r < R; ++r) {
            const float d0 = fmaf(vx[r], qx.x, fmaf(vy[r], qy.x, fmaf(vz[r], qz.x, q2.x)));
            const float d1 = fmaf(vx[r], qx.y, fmaf(vy[r], qy.y, fmaf(vz[r], qz.y, q2.y)));
            m[r] = fminf(fminf(m[r], d0), d1);             // v_min3_f32
        }
#pragma unroll
        for (int r = 0; r < R; ++r) {
            const float d2 = fmaf(vx[r], qx.z, fmaf(vy[r], qy.z, fmaf(vz[r], qz.z, q2.z)));
            const float d3 = fmaf(vx[r], qx.w, fmaf(vy[r], qy.w, fmaf(vz[r], qz.w, q2.w)));
            m[r] = fminf(fminf(m[r], d2), d3);
        }
    }

    // --- epilogue: r2 = p.p = 0.25*(vx^2+vy^2+vz^2); 4 coalesced float4 stores
    float4* dst = (float4*)(ws + (size_t)w * WS_DIR + (size_t)c * WS_CHUNK
                            + b * NUM_PTS + 16 * lt);
#pragma unroll
    for (int k4 = 0; k4 < 4; ++k4) {
        float o[4];
#pragma unroll
        for (int i = 0; i < 4; ++i) {
            const int k = 4 * k4 + i;
            const float r2 = 0.25f * fmaf(vx[k], vx[k], fmaf(vy[k], vy[k], vz[k] * vz[k]));
            o[i] = r2 + m[k];
        }
        dst[k4] = make_float4(o[0], o[1], o[2], o[3]);
    }
}

// Fold 16 chunk partials per row (4 rows/thread via float4), sum, fold KLD.
// 256 blocks x 256 threads cover 2 x 128 x 1024 row slots.
__global__ __launch_bounds__(RT) void reduce_kernel(
    const float* __restrict__ ws,
    const float* __restrict__ mu,
    const float* __restrict__ logvar,
    float* __restrict__ out)
{
    const int gid  = blockIdx.x * RT + threadIdx.x;   // 0..65535
    const int base = gid * 4;                         // flat row slot
    const int dir  = base >> 17;
    const int rem  = base & 131071;                   // b*1024 + row

    const float4* p = (const float4*)(ws + (size_t)dir * WS_DIR + rem);
    float4 mn = p[0];
#pragma unroll
    for (int c = 1; c < NJC; ++c) {
        const float4 q = p[c * (WS_CHUNK / 4)];
        mn.x = fminf(mn.x, q.x);
        mn.y = fminf(mn.y, q.y);
        mn.z = fminf(mn.z, q.z);
        mn.w = fminf(mn.w, q.w);
    }
    float v = (mn.x + mn.y + mn.z + mn.w) * CHAMF_SCALE;

    if (blockIdx.x < 16) {                            // 16*256 = 4096 latents
        const int t = blockIdx.x * RT + threadIdx.x;
        const float lv = logvar[t];
        const float mm = mu[t];
        v += (1.0f + lv - mm * mm - expf(lv)) * KLD_SCALE;
    }

    for (int off = 32; off > 0; off >>= 1)
        v += __shfl_down(v, off, 64);

    __shared__ float red[RT / 64];
    const int lane = threadIdx.x & 63;
    const int wv   = threadIdx.x >> 6;
    if (lane == 0) red[wv] = v;
    __syncthreads();
    if (threadIdx.x == 0) {
        float sum = 0.f;
        for (int wq = 0; wq < RT / 64; ++wq) sum += red[wq];
        atomicAdd(out, sum);
    }
}

extern "C" void kernel_launch(void* const* d_in, const int* in_sizes, int n_in,
                              void* d_out, int out_size, void* d_ws, size_t ws_size,
                              hipStream_t stream) {
    const float* recon_x = (const float*)d_in[0];
    const float* x       = (const float*)d_in[1];
    const float* mu      = (const float*)d_in[2];
    const float* logvar  = (const float*)d_in[3];
    float* out = (float*)d_out;
    float* ws  = (float*)d_ws;            // needs 16.8 MB

    (void)hipMemsetAsync(out, 0, sizeof(float), stream);

    chamfer_part<<<NBATCH * NJC, BT, 0, stream>>>(recon_x, x, ws);
    reduce_kernel<<<256, RT, 0, stream>>>(ws, mu, logvar, out);
}

// Round 12
// 89.090 us; speedup vs baseline: 1.2224x; 1.0536x over previous
//
#include <hip/hip_runtime.h>

#define NUM_PTS 1024
#define NBATCH 128
#define BT 256                       // 4 waves: w = dir + 2*qhalf
#define RT 256
#define NJC 8                        // stored q-chunks per direction (128 pts each)
#define JCH 64                       // points per wave (half chunk)
#define R 16                         // rows per thread (64 lanes x 16 = all 1024)
#define CHAMF_SCALE (1.0f / 1024.0f)
#define KLD_SCALE   (-0.5f * 0.1f / 32.0f)

// ws: float [2][NJC][NBATCH][NUM_PTS] row partials = 8.4 MB.
#define WS_CHUNK (NBATCH * NUM_PTS)          // 131072
#define WS_DIR   (NJC * WS_CHUNK)            // 1048576

// 1024 blocks = (c, b) with b = blockIdx&127: the 8 blocks of one batch share
// a mod-8 dispatch class -> same XCD's L2 serves the batch's rows (vs L3).
// 4 blocks/CU (VGPR<=128, LDS 12.6KB) = 16 waves/CU = 4 waves/SIMD.
// Wave w: dir = w&1 (dir0 rows=x/q=recon -> ref loss_2; dir1 mirrored),
// qhalf = w>>1. Each wave scans its own 64-pt q sub-chunk (wave-private LDS
// planes {x,y,z,q2}; no barrier needed — same-wave DS ops are lgkmcnt-
// ordered). The two q-halves min-combine in-block via stride-17 LDS (2-way
// bank aliasing = free), halving ws vs R10. R=16 rows/thread; d = q2 - 2p.q
// seeded from the q2 plane; r2 recomputed at the store.
__global__ __launch_bounds__(BT, 4) void chamfer_part(
    const float* __restrict__ recon_x,
    const float* __restrict__ x,
    float* __restrict__ ws)
{
    const int b  = blockIdx.x & 127;
    const int c  = blockIdx.x >> 7;          // 0..7
    const int w  = threadIdx.x >> 6;
    const int lt = threadIdx.x & 63;
    const int dir  = w & 1;
    const int half = w >> 1;

    __shared__ float sq[4][4][JCH];          // wave-private q planes, 4 KB
    __shared__ float comb[2][NUM_PTS + 64];  // stride-17 combine buffer, 8.5 KB

    // --- stage this wave's 64-pt q sub-chunk
    {
        const float* qsrc = (dir == 0 ? recon_x : x)
            + (size_t)b * NUM_PTS * 3 + (size_t)(c * 128 + half * JCH + lt) * 3;
        const float qx = qsrc[0], qy = qsrc[1], qz = qsrc[2];
        sq[w][0][lt] = qx;
        sq[w][1][lt] = qy;
        sq[w][2][lt] = qz;
        sq[w][3][lt] = fmaf(qx, qx, fmaf(qy, qy, qz * qz));
    }

    // --- own 16 contiguous rows: 12 coalesced float4 loads, keep -2*coord
    const float* rp = (dir == 0 ? x : recon_x) + (size_t)b * NUM_PTS * 3;
    float vx[R], vy[R], vz[R], m[R];
    {
        float buf[48];
        const float4* __restrict__ s4 = (const float4*)(rp + 48 * lt);
        float4* bp = (float4*)buf;
#pragma unroll
        for (int i = 0; i < 12; ++i) bp[i] = s4[i];
#pragma unroll
        for (int k = 0; k < R; ++k) {
            vx[k] = -2.0f * buf[3 * k + 0];
            vy[k] = -2.0f * buf[3 * k + 1];
            vz[k] = -2.0f * buf[3 * k + 2];
            m[k]  = 1e30f;
        }
    }

    // --- 16 groups x 4 qpts over this wave's sub-chunk
    const float4* __restrict__ qxp = (const float4*)sq[w][0];
    const float4* __restrict__ qyp = (const float4*)sq[w][1];
    const float4* __restrict__ qzp = (const float4*)sq[w][2];
    const float4* __restrict__ q2p = (const float4*)sq[w][3];
#pragma unroll 2
    for (int g = 0; g < JCH / 4; ++g) {
        const float4 qx = qxp[g];
        const float4 qy = qyp[g];
        const float4 qz = qzp[g];
        const float4 q2 = q2p[g];
#pragma unroll
        for (int r = 0; r < R; ++r) {
            const float d0 = fmaf(vx[r], qx.x, fmaf(vy[r], qy.x, fmaf(vz[r], qz.x, q2.x)));
            const float d1 = fmaf(vx[r], qx.y, fmaf(vy[r], qy.y, fmaf(vz[r], qz.y, q2.y)));
            m[r] = fminf(fminf(m[r], d0), d1);            // v_min3_f32
        }
#pragma unroll
        for (int r = 0; r < R; ++r) {
            const float d2 = fmaf(vx[r], qx.z, fmaf(vy[r], qy.z, fmaf(vz[r], qz.z, q2.z)));
            const float d3 = fmaf(vx[r], qx.w, fmaf(vy[r], qy.w, fmaf(vz[r], qz.w, q2.w)));
            m[r] = fminf(fminf(m[r], d2), d3);
        }
    }

    // --- combine q-halves: half 0 publishes (stride 17: lanes lt and lt+32
    //     alias the same bank = free 2-way), half 1 min-combines and stores
    if (half == 0) {
#pragma unroll
        for (int k = 0; k < R; ++k)
            comb[dir][17 * lt + k] = m[k];
    }
    __syncthreads();
    if (half == 1) {
        float4* dst = (float4*)(ws + (size_t)dir * WS_DIR + (size_t)c * WS_CHUNK
                                + b * NUM_PTS + 16 * lt);
#pragma unroll
        for (int k4 = 0; k4 < 4; ++k4) {
            float o[4];
#pragma unroll
            for (int i = 0; i < 4; ++i) {
                const int k = 4 * k4 + i;
                const float mm = fminf(m[k], comb[dir][17 * lt + k]);
                const float r2 = 0.25f * fmaf(vx[k], vx[k],
                                        fmaf(vy[k], vy[k], vz[k] * vz[k]));
                o[i] = r2 + mm;
            }
            dst[k4] = make_float4(o[0], o[1], o[2], o[3]);
        }
    }
}

// Fold 8 chunk partials per row (4 rows/thread via float4), sum, fold KLD.
// 256 blocks x 256 threads cover 2 x 128 x 1024 row slots.
__global__ __launch_bounds__(RT) void reduce_kernel(
    const float* __restrict__ ws,
    const float* __restrict__ mu,
    const float* __restrict__ logvar,
    float* __restrict__ out)
{
    const int gid  = blockIdx.x * RT + threadIdx.x;   // 0..65535
    const int base = gid * 4;
    const int dir  = base >> 17;
    const int rem  = base & 131071;                   // b*1024 + row

    const float4* p = (const float4*)(ws + (size_t)dir * WS_DIR + rem);
    float4 mn = p[0];
#pragma unroll
    for (int c = 1; c < NJC; ++c) {
        const float4 q = p[c * (WS_CHUNK / 4)];
        mn.x = fminf(mn.x, q.x);
        mn.y = fminf(mn.y, q.y);
        mn.z = fminf(mn.z, q.z);
        mn.w = fminf(mn.w, q.w);
    }
    float v = (mn.x + mn.y + mn.z + mn.w) * CHAMF_SCALE;

    if (blockIdx.x < 16) {                            // 16*256 = 4096 latents
        const int t = blockIdx.x * RT + threadIdx.x;
        const float lv = logvar[t];
        const float mm = mu[t];
        v += (1.0f + lv - mm * mm - expf(lv)) * KLD_SCALE;
    }

    for (int off = 32; off > 0; off >>= 1)
        v += __shfl_down(v, off, 64);

    __shared__ float red[RT / 64];
    const int lane = threadIdx.x & 63;
    const int wv   = threadIdx.x >> 6;
    if (lane == 0) red[wv] = v;
    __syncthreads();
    if (threadIdx.x == 0) {
        float sum = 0.f;
        for (int wq = 0; wq < RT / 64; ++wq) sum += red[wq];
        atomicAdd(out, sum);
    }
}

extern "C" void kernel_launch(void* const* d_in, const int* in_sizes, int n_in,
                              void* d_out, int out_size, void* d_ws, size_t ws_size,
                              hipStream_t stream) {
    const float* recon_x = (const float*)d_in[0];
    const float* x       = (const float*)d_in[1];
    const float* mu      = (const float*)d_in[2];
    const float* logvar  = (const float*)d_in[3];
    float* out = (float*)d_out;
    float* ws  = (float*)d_ws;            // needs 8.4 MB

    (void)hipMemsetAsync(out, 0, sizeof(float), stream);

    chamfer_part<<<NBATCH * NJC, BT, 0, stream>>>(recon_x, x, ws);
    reduce_kernel<<<256, RT, 0, stream>>>(ws, mu, logvar, out);
}